// Round 14
// baseline (235.531 us; speedup 1.0000x reference)
//
#include <hip/hip_runtime.h>
#include <hip/hip_bf16.h>
#include <math.h>

// ---------------- problem constants ----------------
#define Dmod   1024
#define NHmod  16
#define DHmod  64
#define Bmod   2
#define Nmod   2048
#define Mrows  (Bmod * Nmod)        // 4096
#define FF     (4 * Dmod)           // 4096
#define EPSLN  1e-5f

typedef __attribute__((ext_vector_type(8))) short bf16x8;
typedef __attribute__((ext_vector_type(4))) float f32x4;
typedef unsigned short ushort_t;
typedef unsigned int uint_t;

#define MFMA16x16x32(a, b, c) __builtin_amdgcn_mfma_f32_16x16x32_bf16((a), (b), (c), 0, 0, 0)

#define AS1 __attribute__((address_space(1)))
#define AS3 __attribute__((address_space(3)))

__device__ __forceinline__ void gload_lds16(const ushort_t* g, ushort_t* l) {
    __builtin_amdgcn_global_load_lds((const AS1 uint_t*)(const void*)g,
                                     (AS3 uint_t*)(void*)l, 16, 0, 0);
}

__device__ __forceinline__ ushort_t f2bf(float f) {
    union { float f; uint_t u; } v; v.f = f;
    uint_t r = v.u + 0x7FFFu + ((v.u >> 16) & 1u);   // RNE
    return (ushort_t)(r >> 16);
}

__device__ __forceinline__ float bf2f(uint_t u) {
    union { float f; uint_t u; } v; v.u = u << 16;
    return v.f;
}

// ---------------- fused fp32->bf16 weight conversion ----------------
// Wq is pre-scaled by 1/sqrt(DH)=0.125 so attention scores need no scaling.
__global__ __launch_bounds__(256) void cvt_kernel(const float* __restrict__ Wq, const float* __restrict__ Wk,
                                                  const float* __restrict__ Wv, const float* __restrict__ Wo,
                                                  const float* __restrict__ W1, const float* __restrict__ W2,
                                                  ushort_t* __restrict__ qkv, ushort_t* __restrict__ wo,
                                                  ushort_t* __restrict__ w1, ushort_t* __restrict__ w2) {
    int u = blockIdx.x * 256 + threadIdx.x;
    const float* src; ushort_t* dst; int i;
    float scale = 1.0f;
    if (u < 393216) {
        if (u < 131072)      { src = Wq; dst = qkv;           i = u; scale = 0.125f; }
        else if (u < 262144) { src = Wk; dst = qkv + 1048576; i = u - 131072; }
        else                 { src = Wv; dst = qkv + 2097152; i = u - 262144; }
    } else if (u < 524288)   { src = Wo; dst = wo; i = u - 393216; }
    else if (u < 1048576)    { src = W1; dst = w1; i = u - 524288; }
    else                     { src = W2; dst = w2; i = u - 1048576; }
    float4 a = ((const float4*)src)[2 * i];
    float4 b = ((const float4*)src)[2 * i + 1];
    uint4 o;
    o.x = (uint_t)f2bf(a.x * scale) | ((uint_t)f2bf(a.y * scale) << 16);
    o.y = (uint_t)f2bf(a.z * scale) | ((uint_t)f2bf(a.w * scale) << 16);
    o.z = (uint_t)f2bf(b.x * scale) | ((uint_t)f2bf(b.y * scale) << 16);
    o.w = (uint_t)f2bf(b.z * scale) | ((uint_t)f2bf(b.w * scale) << 16);
    ((uint4*)dst)[i] = o;
}

// ---------------- LayerNorm -> bf16 out ----------------
__global__ __launch_bounds__(256) void ln_bf_kernel(const float* __restrict__ x,
                                                    const float* __restrict__ scale,
                                                    const float* __restrict__ shift,
                                                    ushort_t* __restrict__ out) {
    int row = blockIdx.x;
    const float4* xr = (const float4*)(x + (size_t)row * Dmod);
    float4 v = xr[threadIdx.x];
    float s  = v.x + v.y + v.z + v.w;
    float s2 = v.x*v.x + v.y*v.y + v.z*v.z + v.w*v.w;

    __shared__ float rs[8], rs2[8];
    #pragma unroll
    for (int o = 32; o; o >>= 1) { s += __shfl_down(s, o); s2 += __shfl_down(s2, o); }
    int wave = threadIdx.x >> 6, lane = threadIdx.x & 63;
    if (lane == 0) { rs[wave] = s; rs2[wave] = s2; }
    __syncthreads();
    if (threadIdx.x == 0) {
        rs[0]  = rs[0] + rs[1] + rs[2] + rs[3];
        rs2[0] = rs2[0] + rs2[1] + rs2[2] + rs2[3];
    }
    __syncthreads();
    float mean = rs[0] * (1.0f / Dmod);
    float var  = rs2[0] * (1.0f / Dmod) - mean * mean;
    float rstd = rsqrtf(var + EPSLN);

    float4 sc = ((const float4*)scale)[threadIdx.x];
    float4 sh = ((const float4*)shift)[threadIdx.x];
    uint2 o;
    o.x = (uint_t)f2bf(sc.x * (v.x - mean) * rstd + sh.x) |
          ((uint_t)f2bf(sc.y * (v.y - mean) * rstd + sh.y) << 16);
    o.y = (uint_t)f2bf(sc.z * (v.z - mean) * rstd + sh.z) |
          ((uint_t)f2bf(sc.w * (v.w - mean) * rstd + sh.w) << 16);
    ((uint2*)(out + (size_t)row * Dmod))[threadIdx.x] = o;
}

// ---------------- GELU via sigmoid identity ----------------
__device__ __forceinline__ float gelu_f(float x) {
    const float c = 0.7978845608028654f;     // sqrt(2/pi)
    float u = c * (x + 0.044715f * x * x * x);
    return x / (1.0f + __expf(-2.0f * u));
}

// ================= 256x256 BK64 8-wave GEMM (m201-geometry) =================
// 512 thr = 8 waves (2M x 4N); per-wave out 128x64; acc[8][4] f32x4.
// LDS 128KB: A[2 dbuf][2 half][128x64], B same.  Stage issued right after the
// per-tile __syncthreads -> ~4 phases (~1400cy) of flight before next drain.
// Both-sides XOR swizzle (stored chunk = global chunk ^ (row&7)); 4 quadrant
// phases x 16 MFMA; inline-asm ds_read_b128 + lgkmcnt(0) + sched_barrier(0)
// (T18) + setprio (T5).
// MODE 0: QKV scatter -> bf16 Q,K head-major + V^T (Nout=3072)
// MODE 2: +bias, GELU -> bf16 [M,Nout]
// MODE 4: bf16 split-K partial -> Cv + bz*M*Nout
template <int MODE>
__global__ __launch_bounds__(512, 2) void gemm256(const ushort_t* __restrict__ A,
                                                  const ushort_t* __restrict__ W,
                                                  const float* __restrict__ bias,
                                                  void* __restrict__ Cv,
                                                  int M, int Nout, int K, int KS,
                                                  int GN, int GM) {
    __shared__ ushort_t Ab[2 * 2 * 8192];   // [dbuf][half][128*64]
    __shared__ ushort_t Bb[2 * 2 * 8192];
    int tid = threadIdx.x;
    int w  = tid >> 6, l = tid & 63;
    int li = l & 15,  g = l >> 4;
    int wm = w >> 2,  wn = w & 3;          // 2 x 4 wave grid

    // ---- XCD-chunked decode ----
    int xcd = blockIdx.x & 7;
    int c   = blockIdx.x >> 3;
    int RN = GN >> 2, RM = GM >> 1;
    int rsz = RN * RM;
    int bz = c / rsz;
    int r  = c - bz * rsz;
    int bm = (xcd >> 2) * RM + r / RN;
    int bn = (xcd & 3) * RN + r % RN;

    // ---- staging source (per-lane, pre-swizzled chunk) ----
    int srow = w * 16 + (l >> 3);
    int scol = ((l & 7) ^ (l >> 3)) * 8;
    const ushort_t* Ag = A + (size_t)(bm * 256 + srow) * K + bz * KS + scol;
    const ushort_t* Wg = W + (size_t)(bn * 256 + srow) * K + bz * KS + scol;

    // ---- read-side bases ----
    uint_t laneoff = (uint_t)(li * 128 + ((g ^ (li & 3)) << 4) + (((li >> 2) & 1) << 6));
    uint_t aB0 = (uint_t)(uintptr_t)(&Ab[0]) + (uint_t)(wm * 16384) + laneoff;
    uint_t bB0 = (uint_t)(uintptr_t)(&Bb[0]) + (uint_t)((wn >> 1) * 16384 + (wn & 1) * 8192) + laneoff;

    f32x4 acc[8][4];
    #pragma unroll
    for (int i = 0; i < 8; i++)
        #pragma unroll
        for (int j = 0; j < 4; j++) acc[i][j] = (f32x4){0.f, 0.f, 0.f, 0.f};

    const int NT = KS >> 6;

    auto stage = [&](int d, int t) {
        int k0 = t * 64;
        #pragma unroll
        for (int h = 0; h < 2; h++) {
            #pragma unroll
            for (int i = 0; i < 2; i++) {
                gload_lds16(Ag + (size_t)(h * 128 + i * 8) * K + k0,
                            &Ab[0] + (d * 2 + h) * 8192 + (w * 2 + i) * 512);
                gload_lds16(Wg + (size_t)(h * 128 + i * 8) * K + k0,
                            &Bb[0] + (d * 2 + h) * 8192 + (w * 2 + i) * 512);
            }
        }
    };

    stage(0, 0);

    for (int t = 0; t < NT; ++t) {
        int d = t & 1;
        __syncthreads();                        // vmcnt(0)+barrier: tile t resident
        if (t + 1 < NT) stage(d ^ 1, t + 1);
        __builtin_amdgcn_sched_barrier(0);

        uint_t aa0 = aB0 + (uint_t)(d * 32768);
        uint_t aa1 = aa0 ^ 64u;
        uint_t bb0 = bB0 + (uint_t)(d * 32768);
        uint_t bb1 = bb0 ^ 64u;

        bf16x8 af0, af1, af2, af3, ag0, ag1, ag2, ag3;
        bf16x8 b000, b010, b001, b011;
        bf16x8 b100, b110, b101, b111;

        // ---- Phase 0: qm=0, qn=0 ----
        asm volatile("ds_read_b128 %0, %1"             : "=v"(af0) : "v"(aa0));
        asm volatile("ds_read_b128 %0, %1 offset:2048" : "=v"(af1) : "v"(aa0));
        asm volatile("ds_read_b128 %0, %1 offset:4096" : "=v"(af2) : "v"(aa0));
        asm volatile("ds_read_b128 %0, %1 offset:6144" : "=v"(af3) : "v"(aa0));
        asm volatile("ds_read_b128 %0, %1"             : "=v"(ag0) : "v"(aa1));
        asm volatile("ds_read_b128 %0, %1 offset:2048" : "=v"(ag1) : "v"(aa1));
        asm volatile("ds_read_b128 %0, %1 offset:4096" : "=v"(ag2) : "v"(aa1));
        asm volatile("ds_read_b128 %0, %1 offset:6144" : "=v"(ag3) : "v"(aa1));
        asm volatile("ds_read_b128 %0, %1"             : "=v"(b000) : "v"(bb0));
        asm volatile("ds_read_b128 %0, %1 offset:2048" : "=v"(b010) : "v"(bb0));
        asm volatile("ds_read_b128 %0, %1"             : "=v"(b001) : "v"(bb1));
        asm volatile("ds_read_b128 %0, %1 offset:2048" : "=v"(b011) : "v"(bb1));
        asm volatile("s_waitcnt lgkmcnt(0)" ::);
        __builtin_amdgcn_sched_barrier(0);
        __builtin_amdgcn_s_setprio(1);
        acc[0][0] = MFMA16x16x32(af0, b000, acc[0][0]); acc[0][0] = MFMA16x16x32(ag0, b001, acc[0][0]);
        acc[1][0] = MFMA16x16x32(af1, b000, acc[1][0]); acc[1][0] = MFMA16x16x32(ag1, b001, acc[1][0]);
        acc[2][0] = MFMA16x16x32(af2, b000, acc[2][0]); acc[2][0] = MFMA16x16x32(ag2, b001, acc[2][0]);
        acc[3][0] = MFMA16x16x32(af3, b000, acc[3][0]); acc[3][0] = MFMA16x16x32(ag3, b001, acc[3][0]);
        acc[0][1] = MFMA16x16x32(af0, b010, acc[0][1]); acc[0][1] = MFMA16x16x32(ag0, b011, acc[0][1]);
        acc[1][1] = MFMA16x16x32(af1, b010, acc[1][1]); acc[1][1] = MFMA16x16x32(ag1, b011, acc[1][1]);
        acc[2][1] = MFMA16x16x32(af2, b010, acc[2][1]); acc[2][1] = MFMA16x16x32(ag2, b011, acc[2][1]);
        acc[3][1] = MFMA16x16x32(af3, b010, acc[3][1]); acc[3][1] = MFMA16x16x32(ag3, b011, acc[3][1]);
        __builtin_amdgcn_s_setprio(0);

        // ---- Phase 1: qm=0, qn=1 ----
        asm volatile("ds_read_b128 %0, %1 offset:4096" : "=v"(b100) : "v"(bb0));
        asm volatile("ds_read_b128 %0, %1 offset:6144" : "=v"(b110) : "v"(bb0));
        asm volatile("ds_read_b128 %0, %1 offset:4096" : "=v"(b101) : "v"(bb1));
        asm volatile("ds_read_b128 %0, %1 offset:6144" : "=v"(b111) : "v"(bb1));
        asm volatile("s_waitcnt lgkmcnt(0)" ::);
        __builtin_amdgcn_sched_barrier(0);
        __builtin_amdgcn_s_setprio(1);
        acc[0][2] = MFMA16x16x32(af0, b100, acc[0][2]); acc[0][2] = MFMA16x16x32(ag0, b101, acc[0][2]);
        acc[1][2] = MFMA16x16x32(af1, b100, acc[1][2]); acc[1][2] = MFMA16x16x32(ag1, b101, acc[1][2]);
        acc[2][2] = MFMA16x16x32(af2, b100, acc[2][2]); acc[2][2] = MFMA16x16x32(ag2, b101, acc[2][2]);
        acc[3][2] = MFMA16x16x32(af3, b100, acc[3][2]); acc[3][2] = MFMA16x16x32(ag3, b101, acc[3][2]);
        acc[0][3] = MFMA16x16x32(af0, b110, acc[0][3]); acc[0][3] = MFMA16x16x32(ag0, b111, acc[0][3]);
        acc[1][3] = MFMA16x16x32(af1, b110, acc[1][3]); acc[1][3] = MFMA16x16x32(ag1, b111, acc[1][3]);
        acc[2][3] = MFMA16x16x32(af2, b110, acc[2][3]); acc[2][3] = MFMA16x16x32(ag2, b111, acc[2][3]);
        acc[3][3] = MFMA16x16x32(af3, b110, acc[3][3]); acc[3][3] = MFMA16x16x32(ag3, b111, acc[3][3]);
        __builtin_amdgcn_s_setprio(0);

        // ---- Phase 2: qm=1, qn=0 ----
        asm volatile("ds_read_b128 %0, %1 offset:8192"  : "=v"(af0) : "v"(aa0));
        asm volatile("ds_read_b128 %0, %1 offset:10240" : "=v"(af1) : "v"(aa0));
        asm volatile("ds_read_b128 %0, %1 offset:12288" : "=v"(af2) : "v"(aa0));
        asm volatile("ds_read_b128 %0, %1 offset:14336" : "=v"(af3) : "v"(aa0));
        asm volatile("ds_read_b128 %0, %1 offset:8192"  : "=v"(ag0) : "v"(aa1));
        asm volatile("ds_read_b128 %0, %1 offset:10240" : "=v"(ag1) : "v"(aa1));
        asm volatile("ds_read_b128 %0, %1 offset:12288" : "=v"(ag2) : "v"(aa1));
        asm volatile("ds_read_b128 %0, %1 offset:14336" : "=v"(ag3) : "v"(aa1));
        asm volatile("s_waitcnt lgkmcnt(0)" ::);
        __builtin_amdgcn_sched_barrier(0);
        __builtin_amdgcn_s_setprio(1);
        acc[4][0] = MFMA16x16x32(af0, b000, acc[4][0]); acc[4][0] = MFMA16x16x32(ag0, b001, acc[4][0]);
        acc[5][0] = MFMA16x16x32(af1, b000, acc[5][0]); acc[5][0] = MFMA16x16x32(ag1, b001, acc[5][0]);
        acc[6][0] = MFMA16x16x32(af2, b000, acc[6][0]); acc[6][0] = MFMA16x16x32(ag2, b001, acc[6][0]);
        acc[7][0] = MFMA16x16x32(af3, b000, acc[7][0]); acc[7][0] = MFMA16x16x32(ag3, b001, acc[7][0]);
        acc[4][1] = MFMA16x16x32(af0, b010, acc[4][1]); acc[4][1] = MFMA16x16x32(ag0, b011, acc[4][1]);
        acc[5][1] = MFMA16x16x32(af1, b010, acc[5][1]); acc[5][1] = MFMA16x16x32(ag1, b011, acc[5][1]);
        acc[6][1] = MFMA16x16x32(af2, b010, acc[6][1]); acc[6][1] = MFMA16x16x32(ag2, b011, acc[6][1]);
        acc[7][1] = MFMA16x16x32(af3, b010, acc[7][1]); acc[7][1] = MFMA16x16x32(ag3, b011, acc[7][1]);
        __builtin_amdgcn_s_setprio(0);

        // ---- Phase 3: qm=1, qn=1 ----
        __builtin_amdgcn_s_setprio(1);
        acc[4][2] = MFMA16x16x32(af0, b100, acc[4][2]); acc[4][2] = MFMA16x16x32(ag0, b101, acc[4][2]);
        acc[5][2] = MFMA16x16x32(af1, b100, acc[5][2]); acc[5][2] = MFMA16x16x32(ag1, b101, acc[5][2]);
        acc[6][2] = MFMA16x16x32(af2, b100, acc[6][2]); acc[6][2] = MFMA16x16x32(ag2, b101, acc[6][2]);
        acc[7][2] = MFMA16x16x32(af3, b100, acc[7][2]); acc[7][2] = MFMA16x16x32(ag3, b101, acc[7][2]);
        acc[4][3] = MFMA16x16x32(af0, b110, acc[4][3]); acc[4][3] = MFMA16x16x32(ag0, b111, acc[4][3]);
        acc[5][3] = MFMA16x16x32(af1, b110, acc[5][3]); acc[5][3] = MFMA16x16x32(ag1, b111, acc[5][3]);
        acc[6][3] = MFMA16x16x32(af2, b110, acc[6][3]); acc[6][3] = MFMA16x16x32(ag2, b111, acc[6][3]);
        acc[7][3] = MFMA16x16x32(af3, b110, acc[7][3]); acc[7][3] = MFMA16x16x32(ag3, b111, acc[7][3]);
        __builtin_amdgcn_s_setprio(0);
    }

    // ---- epilogue ----
    #pragma unroll
    for (int fm = 0; fm < 8; fm++) {
        #pragma unroll
        for (int fn = 0; fn < 4; fn++) {
            int nn = bn * 256 + wn * 64 + (fn >> 1) * 32 + (fn & 1) * 16 + li;
            #pragma unroll
            for (int r2 = 0; r2 < 4; r2++) {
                int m = bm * 256 + wm * 128 + (fm >> 2) * 64 + (fm & 3) * 16 + g * 4 + r2;
                float v = acc[fm][fn][r2];
                if (MODE == 2) {
                    ushort_t* C = (ushort_t*)Cv;
                    C[(size_t)m * Nout + nn] = f2bf(gelu_f(v + bias[nn]));
                } else if (MODE == 4) {  // bf16 split-K partial
                    ushort_t* P = (ushort_t*)Cv + (size_t)bz * M * Nout;
                    P[(size_t)m * Nout + nn] = f2bf(v);
                } else {                 // MODE 0: QKV scatter
                    int which = nn >> 10;
                    int col   = nn & 1023;
                    int h = col >> 6, d = col & 63;
                    int b = m >> 11,  n = m & (Nmod - 1);
                    ushort_t* C = (ushort_t*)Cv;
                    if (which == 0)
                        C[(((size_t)(b * NHmod + h)) * Nmod + n) * DHmod + d] = f2bf(v);
                    else if (which == 1)
                        C[4194304u + (((size_t)(b * NHmod + h)) * Nmod + n) * DHmod + d] = f2bf(v);
                    else
                        C[8388608u + (((size_t)(b * NHmod + h)) * DHmod + d) * Nmod + n] = f2bf(v);
                }
            }
        }
    }
}

// ---------------- bf16 MFMA GEMM (round-12, kept for Wo split-K) ----------------
template <int MODE, int BN>
__global__ __launch_bounds__(256) void bgemm(const ushort_t* __restrict__ A,
                                             const ushort_t* __restrict__ W,
                                             const float* __restrict__ bias,
                                             const float* __restrict__ resid,
                                             void* __restrict__ Cv,
                                             int M, int Nout, int K, int KS,
                                             int GN, int GM) {
    const int BSZ = BN * 32;
    const int NFR = BN / 32;
    __shared__ ushort_t As[3 * 4096];
    __shared__ ushort_t Bs[3 * BSZ];
    int tid  = threadIdx.x;
    int w    = tid >> 6, lane = tid & 63;
    int li   = lane & 15, g = lane >> 4;
    int wr   = w >> 1,  wc = w & 1;

    int xcd = blockIdx.x & 7;
    int c   = blockIdx.x >> 3;
    int RN  = GN >> 2;
    int RM  = GM >> 1;
    int rsz = RN * RM;
    int bz  = c / rsz;
    int r   = c - bz * rsz;
    int bm  = (xcd >> 2) * RM + r / RN;
    int bn  = (xcd & 3) * RN + r % RN;

    int srow = tid >> 2;
    int scol = ((tid & 3) ^ ((tid >> 3) & 3)) * 8;
    const ushort_t* Ag = A + (size_t)(bm * 128 + srow) * K + bz * KS + scol;
    const ushort_t* Wg = W + (size_t)(bn * BN  + srow) * K + bz * KS + scol;
    ushort_t* AsW = As + w * 512;
    ushort_t* BsW = Bs + w * 512;

    int rsw = ((g ^ ((li >> 1) & 3)) * 8);

    uint_t lbA = (uint_t)(uintptr_t)(&As[0]);
    uint_t lbB = (uint_t)(uintptr_t)(&Bs[0]);
    uint_t abase = lbA + (uint_t)(((wr * 64 + li) * 32 + rsw) * 2);
    uint_t bbase = lbB + (uint_t)(((wc * (BN / 2) + li) * 32 + rsw) * 2);

    f32x4 acc[4][NFR];
    #pragma unroll
    for (int i = 0; i < 4; i++)
        #pragma unroll
        for (int j = 0; j < NFR; j++) acc[i][j] = (f32x4){0.f, 0.f, 0.f, 0.f};

    const int NT = KS >> 5;

    auto stagef = [&](int bufA, int bufB, int t) {
        int k0 = t * 32;
        gload_lds16(Ag + k0,          AsW + bufA);
        gload_lds16(Ag + 64 * K + k0, AsW + bufA + 2048);
        gload_lds16(Wg + k0,          BsW + bufB);
        if (BN == 128) gload_lds16(Wg + 64 * K + k0, BsW + bufB + 2048);
    };

    stagef(0, 0, 0);
    stagef(4096, BSZ, 1);

    int curA = 0, curB = 0;
    int stgA = 8192, stgB = 2 * BSZ;

    for (int t = 0; t < NT; ++t) {
        if (t == NT - 1) { asm volatile("s_waitcnt vmcnt(0)" ::); }
        else if (BN == 128) { asm volatile("s_waitcnt vmcnt(4)" ::); }
        else { asm volatile("s_waitcnt vmcnt(3)" ::); }
        __builtin_amdgcn_s_barrier();
        __builtin_amdgcn_sched_barrier(0);
        if (t + 2 < NT) stagef(stgA, stgB, t + 2);
        __builtin_amdgcn_sched_barrier(0);
        bf16x8 af[4], bfr[NFR];
        uint_t aa = abase + (uint_t)(curA * 2);
        uint_t bb = bbase + (uint_t)(curB * 2);
        asm volatile("ds_read_b128 %0, %1"             : "=v"(af[0]) : "v"(aa));
        asm volatile("ds_read_b128 %0, %1 offset:1024" : "=v"(af[1]) : "v"(aa));
        asm volatile("ds_read_b128 %0, %1 offset:2048" : "=v"(af[2]) : "v"(aa));
        asm volatile("ds_read_b128 %0, %1 offset:3072" : "=v"(af[3]) : "v"(aa));
        asm volatile("ds_read_b128 %0, %1"             : "=v"(bfr[0]) : "v"(bb));
        asm volatile("ds_read_b128 %0, %1 offset:1024" : "=v"(bfr[1]) : "v"(bb));
        if (NFR == 4) {
            asm volatile("ds_read_b128 %0, %1 offset:2048" : "=v"(bfr[2]) : "v"(bb));
            asm volatile("ds_read_b128 %0, %1 offset:3072" : "=v"(bfr[3]) : "v"(bb));
        }
        asm volatile("s_waitcnt lgkmcnt(0)" ::);
        __builtin_amdgcn_sched_barrier(0);
        __builtin_amdgcn_s_setprio(1);
        #pragma unroll
        for (int mi = 0; mi < 4; mi++)
            #pragma unroll
            for (int ni = 0; ni < NFR; ni++)
                acc[mi][ni] = MFMA16x16x32(af[mi], bfr[ni], acc[mi][ni]);
        __builtin_amdgcn_s_setprio(0);
        curA = (curA == 8192) ? 0 : curA + 4096;
        curB = (curB == 2 * BSZ) ? 0 : curB + BSZ;
        stgA = (stgA == 8192) ? 0 : stgA + 4096;
        stgB = (stgB == 2 * BSZ) ? 0 : stgB + BSZ;
    }

    #pragma unroll
    for (int mi = 0; mi < 4; mi++) {
        #pragma unroll
        for (int ni = 0; ni < NFR; ni++) {
            int nn = bn * BN + wc * (BN / 2) + ni * 16 + li;
            #pragma unroll
            for (int r2 = 0; r2 < 4; r2++) {
                int m = bm * 128 + wr * 64 + mi * 16 + g * 4 + r2;
                float v = acc[mi][ni][r2];
                if (MODE == 1) {
                    float* C = (float*)Cv;
                    C[(size_t)m * Nout + nn] = v + bias[nn] + resid[(size_t)m * Nout + nn];
                } else if (MODE == 3) {
                    float* C = (float*)Cv + (size_t)bz * M * Nout;
                    C[(size_t)m * Nout + nn] = v;
                }
            }
        }
    }
}

// ---------------- split-K reduce + residual + LN (Wo path, 2 fp32 partials) ----------------
__global__ __launch_bounds__(256) void red_ln_kernel(const float* __restrict__ p,
                                                     const float* __restrict__ x,
                                                     const float* __restrict__ bo,
                                                     const float* __restrict__ scale,
                                                     const float* __restrict__ shift,
                                                     float* __restrict__ x1,
                                                     ushort_t* __restrict__ h2) {
    int row = blockIdx.x;
    int t   = threadIdx.x;
    const size_t MD = (size_t)Mrows * Dmod;
    float4 a = ((const float4*)(p + (size_t)row * Dmod))[t];
    float4 b = ((const float4*)(p + MD + (size_t)row * Dmod))[t];
    float4 xr = ((const float4*)(x + (size_t)row * Dmod))[t];
    float4 bb = ((const float4*)bo)[t];
    float4 v;
    v.x = a.x + b.x + xr.x + bb.x;
    v.y = a.y + b.y + xr.y + bb.y;
    v.z = a.z + b.z + xr.z + bb.z;
    v.w = a.w + b.w + xr.w + bb.w;
    ((float4*)(x1 + (size_t)row * Dmod))[t] = v;

    float s  = v.x + v.y + v.z + v.w;
    float s2 = v.x*v.x + v.y*v.y + v.z*v.z + v.w*v.w;
    __shared__ float rs[8], rs2[8];
    #pragma unroll
    for (int o = 32; o; o >>= 1) { s += __shfl_down(s, o); s2 += __shfl_down(s2, o); }
    int wave = t >> 6, lane = t & 63;
    if (lane == 0) { rs[wave] = s; rs2[wave] = s2; }
    __syncthreads();
    if (t == 0) {
        rs[0]  = rs[0] + rs[1] + rs[2] + rs[3];
        rs2[0] = rs2[0] + rs2[1] + rs2[2] + rs2[3];
    }
    __syncthreads();
    float mean = rs[0] * (1.0f / Dmod);
    float var  = rs2[0] * (1.0f / Dmod) - mean * mean;
    float rstd = rsqrtf(var + EPSLN);

    float4 sc = ((const float4*)scale)[t];
    float4 sh = ((const float4*)shift)[t];
    uint2 o;
    o.x = (uint_t)f2bf(sc.x * (v.x - mean) * rstd + sh.x) |
          ((uint_t)f2bf(sc.y * (v.y - mean) * rstd + sh.y) << 16);
    o.y = (uint_t)f2bf(sc.z * (v.z - mean) * rstd + sh.z) |
          ((uint_t)f2bf(sc.w * (v.w - mean) * rstd + sh.w) << 16);
    ((uint2*)(h2 + (size_t)row * Dmod))[t] = o;
}

// ---------------- 4-way bf16 split-K reduce + bias + residual (FFN-down) ----------------
__global__ __launch_bounds__(256) void red_out4_kernel(const ushort_t* __restrict__ p,
                                                       const float* __restrict__ x1,
                                                       const float* __restrict__ b2,
                                                       float* __restrict__ out) {
    const size_t MD4 = (size_t)Mrows * Dmod / 4;
    size_t i = (size_t)blockIdx.x * 256 + threadIdx.x;
    if (i >= MD4) return;
    float4 xr = ((const float4*)x1)[i];
    float4 bb = ((const float4*)b2)[i & 255];
    float4 v;
    v.x = xr.x + bb.x; v.y = xr.y + bb.y; v.z = xr.z + bb.z; v.w = xr.w + bb.w;
    #pragma unroll
    for (int z = 0; z < 4; z++) {
        uint2 pk = ((const uint2*)(p + (size_t)z * Mrows * Dmod))[i];
        v.x += bf2f(pk.x & 0xffffu);
        v.y += bf2f(pk.x >> 16);
        v.z += bf2f(pk.y & 0xffffu);
        v.w += bf2f(pk.y >> 16);
    }
    ((float4*)out)[i] = v;
}

// ---------------- Flash attention v4 (unchanged) ----------------
__global__ __launch_bounds__(256) void fattn_kernel(const ushort_t* __restrict__ Q,
                                                    const ushort_t* __restrict__ K,
                                                    const ushort_t* __restrict__ VT,
                                                    ushort_t* __restrict__ O) {
    int bid = blockIdx.x;
    int xcd = bid & 7;
    int j   = bid >> 3;
    int bh  = xcd * 4 + (j & 3);
    int qt  = 31 - (j >> 2);
    int b   = bh >> 4, hh = bh & 15;
    int w    = threadIdx.x >> 6;
    int lane = threadIdx.x & 63;
    int li   = lane & 15;
    int g    = lane >> 4;

    __shared__ ushort_t Klds[2][4096];
    __shared__ ushort_t Vlds[2][4096];
    __shared__ ushort_t Plds[4][16][72];

    int q0 = qt * 64 + w * 16;
    int q  = q0 + li;

    const ushort_t* Qb = Q  + (size_t)bh * Nmod * DHmod;
    const ushort_t* Kb = K  + (size_t)bh * Nmod * DHmod;
    const ushort_t* Vb = VT + (size_t)bh * DHmod * Nmod;

    bf16x8 qf[2];
    #pragma unroll
    for (int c = 0; c < 2; c++)
        qf[c] = *(const bf16x8*)(Qb + (size_t)q * DHmod + c * 32 + g * 8);

    f32x4 po[4];
    #pragma unroll
    for (int mt = 0; mt < 4; mt++) po[mt] = (f32x4){0.f, 0.f, 0.f, 0.f};
    float l = 0.f;

    const int ntiles = qt + 1;

    int r_sub = lane >> 3;
    int cc    = ((lane & 7) ^ (r_sub & 7)) * 8;

    int swz  = (li & 7) * 8;
    int roff = li * 64;
    int c0k  = (g * 8) ^ swz;
    int c1k  = (32 + g * 8) ^ swz;

    auto stage = [&](int buf, int kt) {
        int k0 = kt * 64;
        #pragma unroll
        for (int i2 = 0; i2 < 2; i2++) {
            int i   = w * 2 + i2;
            int row = i * 8 + r_sub;
            gload_lds16(Kb + (size_t)(k0 + row) * DHmod + cc, &Klds[buf][i * 512]);
            gload_lds16(Vb + (size_t)row * Nmod + k0 + cc,    &Vlds[buf][i * 512]);
        }
    };

    stage(0, 0);

    for (int kt = 0; kt < ntiles; ++kt) {
        __syncthreads();
        if (kt + 1 < ntiles) stage((kt + 1) & 1, kt + 1);
        int cur = kt & 1;
        int k0  = kt * 64;

        f32x4 s[4];
        __builtin_amdgcn_s_setprio(1);
        #pragma unroll
        for (int mt = 0; mt < 4; mt++) {
            bf16x8 kf0 = *(const bf16x8*)&Klds[cur][mt * 1024 + roff + c0k];
            bf16x8 kf1 = *(const bf16x8*)&Klds[cur][mt * 1024 + roff + c1k];
            s[mt] = (f32x4){0.f, 0.f, 0.f, 0.f};
            s[mt] = MFMA16x16x32(kf0, qf[0], s[mt]);
            s[mt] = MFMA16x16x32(kf1, qf[1], s[mt]);
        }
        __builtin_amdgcn_s_setprio(0);

        if (kt == qt) {
            #pragma unroll
            for (int mt = 0; mt < 4; mt++)
                #pragma unroll
                for (int r = 0; r < 4; r++)
                    if (k0 + mt * 16 + g * 4 + r > q) s[mt][r] = -INFINITY;
        }
        float ptile = 0.f;
        #pragma unroll
        for (int mt = 0; mt < 4; mt++) {
            float p0 = __expf(s[mt][0]);
            float p1 = __expf(s[mt][1]);
            float p2 = __expf(s[mt][2]);
            float p3 = __expf(s[mt][3]);
            ptile += (p0 + p1) + (p2 + p3);
            uint2 pk;
            pk.x = (uint_t)f2bf(p0) | ((uint_t)f2bf(p1) << 16);
            pk.y = (uint_t)f2bf(p2) | ((uint_t)f2bf(p3) << 16);
            *(uint2*)&Plds[w][li][mt * 16 + g * 4] = pk;
        }
        l += ptile;

        asm volatile("" ::: "memory");

        bf16x8 pf0 = *(const bf16x8*)&Plds[w][li][g * 8];
        bf16x8 pf1 = *(const bf16x8*)&Plds[w][li][32 + g * 8];
        __builtin_amdgcn_s_setprio(1);
        #pragma unroll
        for (int mt = 0; mt < 4; mt++) {
            bf16x8 vf0 = *(const bf16x8*)&Vlds[cur][mt * 1024 + roff + c0k];
            bf16x8 vf1 = *(const bf16x8*)&Vlds[cur][mt * 1024 + roff + c1k];
            po[mt] = MFMA16x16x32(vf0, pf0, po[mt]);
            po[mt] = MFMA16x16x32(vf1, pf1, po[mt]);
        }
        __builtin_amdgcn_s_setprio(0);
        asm volatile("" ::: "memory");
    }

    l += __shfl_xor(l, 16);
    l += __shfl_xor(l, 32);
    float inv = 1.0f / l;
    ushort_t* Orow = O + ((size_t)(b * Nmod + q)) * Dmod + hh * DHmod;
    #pragma unroll
    for (int mt = 0; mt < 4; mt++) {
        uint2 pk;
        pk.x = (uint_t)f2bf(po[mt][0] * inv) | ((uint_t)f2bf(po[mt][1] * inv) << 16);
        pk.y = (uint_t)f2bf(po[mt][2] * inv) | ((uint_t)f2bf(po[mt][3] * inv) << 16);
        *(uint2*)(Orow + mt * 16 + g * 4) = pk;
    }
}

// ---------------- launcher ----------------
extern "C" void kernel_launch(void* const* d_in, const int* in_sizes, int n_in,
                              void* d_out, int out_size, void* d_ws, size_t ws_size,
                              hipStream_t stream) {
    const float* x    = (const float*)d_in[0];
    const float* Wq   = (const float*)d_in[1];
    const float* Wk   = (const float*)d_in[2];
    const float* Wv   = (const float*)d_in[3];
    const float* Wo   = (const float*)d_in[4];
    const float* bo   = (const float*)d_in[5];
    const float* ln1s = (const float*)d_in[6];
    const float* ln1b = (const float*)d_in[7];
    const float* ln2s = (const float*)d_in[8];
    const float* ln2b = (const float*)d_in[9];
    const float* W1   = (const float*)d_in[10];
    const float* b1   = (const float*)d_in[11];
    const float* W2   = (const float*)d_in[12];
    const float* b2   = (const float*)d_in[13];
    float* out = (float*)d_out;
    char*  wsb = (char*)d_ws;

    // workspace layout (112 MB)
    ushort_t* h_bf  = (ushort_t*)wsb;                  // 8MB  LN1 out; reused as att
    ushort_t* qb    = (ushort_t*)(wsb + (8u  << 20));  // 8MB  Q
    ushort_t* kb    = qb + 4194304;                    // 8MB  K
    ushort_t* vtb   = qb + 8388608;                    // 8MB  V^T
    float*    x1    = (float*)(wsb + (32u << 20));     // 16MB x + attn
    ushort_t* h2_bf = (ushort_t*)(wsb + (48u << 20));  // 8MB  LN2 out
    ushort_t* g_bf  = (ushort_t*)(wsb + (56u << 20));  // 32MB FFN hidden
    ushort_t* wqkv  = (ushort_t*)(wsb + (88u << 20));  // 6MB
    ushort_t* wo_b  = (ushort_t*)(wsb + (94u << 20));  // 2MB
    ushort_t* w1_b  = (ushort_t*)(wsb + (96u << 20));  // 8MB
    ushort_t* w2_b  = (ushort_t*)(wsb + (104u << 20)); // 8MB
    ushort_t* att   = h_bf;
    // split-K partial regions:
    float*    pWo = (float*)(wsb + (56u << 20));       // 2 x 16MB fp32 (g region, free until FFN-up)
    ushort_t* pFd = (ushort_t*)wsb;                    // 4 x 8MB bf16 (h/q/k/v region, free after Wo)

    cvt_kernel<<<6144, 256, 0, stream>>>(Wq, Wk, Wv, Wo, W1, W2, wqkv, wo_b, w1_b, w2_b);
    ln_bf_kernel<<<Mrows, 256, 0, stream>>>(x, ln1s, ln1b, h_bf);
    // QKV: 256x256 8-wave, GN=12, GM=16 -> 192 blocks
    gemm256<0><<<192, 512, 0, stream>>>(h_bf, wqkv, nullptr, qb, Mrows, 3072, Dmod, Dmod, 12, 16);
    fattn_kernel<<<1024, 256, 0, stream>>>(qb, kb, vtb, att);
    // Wo split-K=2 (128-tile kernel): GN=16, GM=32, z=2 -> 1024 blocks
    bgemm<3, 64><<<1024, 256, 0, stream>>>(att, wo_b, nullptr, nullptr, pWo, Mrows, Dmod, Dmod, Dmod / 2, 16, 32);
    red_ln_kernel<<<Mrows, 256, 0, stream>>>(pWo, x, bo, ln2s, ln2b, x1, h2_bf);
    // FFN up: 256x256 8-wave, GN=16, GM=16 -> 256 blocks
    gemm256<2><<<256, 512, 0, stream>>>(h2_bf, w1_b, b1, g_bf, Mrows, FF, Dmod, Dmod, 16, 16);
    // FFN down: 256x256 8-wave, split-K=4 (bf16 partials), GN=4, GM=16 -> 256 blocks
    gemm256<4><<<256, 512, 0, stream>>>(g_bf, w2_b, nullptr, pFd, Mrows, Dmod, FF, FF / 4, 4, 16);
    red_out4_kernel<<<(Mrows * Dmod / 4 + 255) / 256, 256, 0, stream>>>(pFd, x1, b2, out);
}

// Round 15
// 220.569 us; speedup vs baseline: 1.0678x; 1.0678x over previous
//
#include <hip/hip_runtime.h>
#include <hip/hip_bf16.h>
#include <math.h>

// ---------------- problem constants ----------------
#define Dmod   1024
#define NHmod  16
#define DHmod  64
#define Bmod   2
#define Nmod   2048
#define Mrows  (Bmod * Nmod)        // 4096
#define FF     (4 * Dmod)           // 4096
#define EPSLN  1e-5f

typedef __attribute__((ext_vector_type(8))) short bf16x8;
typedef __attribute__((ext_vector_type(4))) float f32x4;
typedef unsigned short ushort_t;
typedef unsigned int uint_t;

#define MFMA16x16x32(a, b, c) __builtin_amdgcn_mfma_f32_16x16x32_bf16((a), (b), (c), 0, 0, 0)

#define AS1 __attribute__((address_space(1)))
#define AS3 __attribute__((address_space(3)))

__device__ __forceinline__ void gload_lds16(const ushort_t* g, ushort_t* l) {
    __builtin_amdgcn_global_load_lds((const AS1 uint_t*)(const void*)g,
                                     (AS3 uint_t*)(void*)l, 16, 0, 0);
}

__device__ __forceinline__ ushort_t f2bf(float f) {
    union { float f; uint_t u; } v; v.f = f;
    uint_t r = v.u + 0x7FFFu + ((v.u >> 16) & 1u);   // RNE
    return (ushort_t)(r >> 16);
}

__device__ __forceinline__ float bf2f(uint_t u) {
    union { float f; uint_t u; } v; v.u = u << 16;
    return v.f;
}

// ---------------- fused fp32->bf16 weight conversion ----------------
__global__ __launch_bounds__(256) void cvt_kernel(const float* __restrict__ Wq, const float* __restrict__ Wk,
                                                  const float* __restrict__ Wv, const float* __restrict__ Wo,
                                                  const float* __restrict__ W1, const float* __restrict__ W2,
                                                  ushort_t* __restrict__ qkv, ushort_t* __restrict__ wo,
                                                  ushort_t* __restrict__ w1, ushort_t* __restrict__ w2) {
    int u = blockIdx.x * 256 + threadIdx.x;
    const float* src; ushort_t* dst; int i;
    float scale = 1.0f;
    if (u < 393216) {
        if (u < 131072)      { src = Wq; dst = qkv;           i = u; scale = 0.125f; }
        else if (u < 262144) { src = Wk; dst = qkv + 1048576; i = u - 131072; }
        else                 { src = Wv; dst = qkv + 2097152; i = u - 262144; }
    } else if (u < 524288)   { src = Wo; dst = wo; i = u - 393216; }
    else if (u < 1048576)    { src = W1; dst = w1; i = u - 524288; }
    else                     { src = W2; dst = w2; i = u - 1048576; }
    float4 a = ((const float4*)src)[2 * i];
    float4 b = ((const float4*)src)[2 * i + 1];
    uint4 o;
    o.x = (uint_t)f2bf(a.x * scale) | ((uint_t)f2bf(a.y * scale) << 16);
    o.y = (uint_t)f2bf(a.z * scale) | ((uint_t)f2bf(a.w * scale) << 16);
    o.z = (uint_t)f2bf(b.x * scale) | ((uint_t)f2bf(b.y * scale) << 16);
    o.w = (uint_t)f2bf(b.z * scale) | ((uint_t)f2bf(b.w * scale) << 16);
    ((uint4*)dst)[i] = o;
}

// ---------------- LayerNorm -> bf16 out ----------------
__global__ __launch_bounds__(256) void ln_bf_kernel(const float* __restrict__ x,
                                                    const float* __restrict__ scale,
                                                    const float* __restrict__ shift,
                                                    ushort_t* __restrict__ out) {
    int row = blockIdx.x;
    const float4* xr = (const float4*)(x + (size_t)row * Dmod);
    float4 v = xr[threadIdx.x];
    float s  = v.x + v.y + v.z + v.w;
    float s2 = v.x*v.x + v.y*v.y + v.z*v.z + v.w*v.w;

    __shared__ float rs[8], rs2[8];
    #pragma unroll
    for (int o = 32; o; o >>= 1) { s += __shfl_down(s, o); s2 += __shfl_down(s2, o); }
    int wave = threadIdx.x >> 6, lane = threadIdx.x & 63;
    if (lane == 0) { rs[wave] = s; rs2[wave] = s2; }
    __syncthreads();
    if (threadIdx.x == 0) {
        rs[0]  = rs[0] + rs[1] + rs[2] + rs[3];
        rs2[0] = rs2[0] + rs2[1] + rs2[2] + rs2[3];
    }
    __syncthreads();
    float mean = rs[0] * (1.0f / Dmod);
    float var  = rs2[0] * (1.0f / Dmod) - mean * mean;
    float rstd = rsqrtf(var + EPSLN);

    float4 sc = ((const float4*)scale)[threadIdx.x];
    float4 sh = ((const float4*)shift)[threadIdx.x];
    uint2 o;
    o.x = (uint_t)f2bf(sc.x * (v.x - mean) * rstd + sh.x) |
          ((uint_t)f2bf(sc.y * (v.y - mean) * rstd + sh.y) << 16);
    o.y = (uint_t)f2bf(sc.z * (v.z - mean) * rstd + sh.z) |
          ((uint_t)f2bf(sc.w * (v.w - mean) * rstd + sh.w) << 16);
    ((uint2*)(out + (size_t)row * Dmod))[threadIdx.x] = o;
}

// ---------------- GELU via sigmoid identity ----------------
__device__ __forceinline__ float gelu_f(float x) {
    const float c = 0.7978845608028654f;     // sqrt(2/pi)
    float u = c * (x + 0.044715f * x * x * x);
    return x / (1.0f + __expf(-2.0f * u));
}

// ================ 256x256 BK64 8-wave GEMM, FULL 8-PHASE (m201 port) ================
// 512 thr = 8 waves (2M x 4N); per-wave out 128x64; acc[8][4].
// LDS per operand: [2 dbuf][2 K-half][256 rows as 128 lds-rows x 128B] = 64KB; total 128KB.
// K-half h = k-cols [h*32, h*32+32).  Phases per K-tile: (qm0,kk0),(qm1,kk0),(qm0,kk1),(qm1,kk1)
// with 8/4/8/4 ds_read_b128; B-frags (4) reused across qm pair.
// Stage 1 half-tile (2 gload_lds/thread) per phase, order [A-h0,B-h0,A-h1,B-h1] of tile t+1.
// Counted vmcnt(4) at ends of p1 (protects tile t's kk1 halves) and p3 (tile t+1's kk0 halves);
// last tile p1 uses vmcnt(0).  Per phase: reads; stage; barrier; lgkmcnt(0); sched_barrier;
// setprio(1); 16 MFMA; setprio(0); [vmcnt]; barrier.   (T3+T4+T5, T18 fences)
// Swizzle (both-sides, rule #21): 128B lds-row j packs data-rows {2j,2j+1}; stored chunk
// position p holds logical chunk p^(j&7); source lane l pre-fetches lc=(l&7)^(l>>3);
// read chunk ((li&1)*4+g)^(li>>1) -> 2 lanes/bank-quad per 16-lane group = conflict-free.
// MODE 0: QKV scatter (Q,K head-major + V^T vectorized); 2: +bias GELU bf16; 4: bf16 split-K partial.
#define DSR(D, A, OFF) asm volatile("ds_read_b128 %0, %1 offset:" OFF : "=v"(D) : "v"(A))
#define SB0 __builtin_amdgcn_sched_barrier(0)
#define BARR __builtin_amdgcn_s_barrier()
#define LGKM0 asm volatile("s_waitcnt lgkmcnt(0)" ::)

#define MMQ0 \
  acc[0][0]=MFMA16x16x32(a0,b0,acc[0][0]); acc[1][0]=MFMA16x16x32(a1,b0,acc[1][0]); \
  acc[2][0]=MFMA16x16x32(a2,b0,acc[2][0]); acc[3][0]=MFMA16x16x32(a3,b0,acc[3][0]); \
  acc[0][1]=MFMA16x16x32(a0,b1,acc[0][1]); acc[1][1]=MFMA16x16x32(a1,b1,acc[1][1]); \
  acc[2][1]=MFMA16x16x32(a2,b1,acc[2][1]); acc[3][1]=MFMA16x16x32(a3,b1,acc[3][1]); \
  acc[0][2]=MFMA16x16x32(a0,b2,acc[0][2]); acc[1][2]=MFMA16x16x32(a1,b2,acc[1][2]); \
  acc[2][2]=MFMA16x16x32(a2,b2,acc[2][2]); acc[3][2]=MFMA16x16x32(a3,b2,acc[3][2]); \
  acc[0][3]=MFMA16x16x32(a0,b3,acc[0][3]); acc[1][3]=MFMA16x16x32(a1,b3,acc[1][3]); \
  acc[2][3]=MFMA16x16x32(a2,b3,acc[2][3]); acc[3][3]=MFMA16x16x32(a3,b3,acc[3][3]);
#define MMQ4 \
  acc[4][0]=MFMA16x16x32(a0,b0,acc[4][0]); acc[5][0]=MFMA16x16x32(a1,b0,acc[5][0]); \
  acc[6][0]=MFMA16x16x32(a2,b0,acc[6][0]); acc[7][0]=MFMA16x16x32(a3,b0,acc[7][0]); \
  acc[4][1]=MFMA16x16x32(a0,b1,acc[4][1]); acc[5][1]=MFMA16x16x32(a1,b1,acc[5][1]); \
  acc[6][1]=MFMA16x16x32(a2,b1,acc[6][1]); acc[7][1]=MFMA16x16x32(a3,b1,acc[7][1]); \
  acc[4][2]=MFMA16x16x32(a0,b2,acc[4][2]); acc[5][2]=MFMA16x16x32(a1,b2,acc[5][2]); \
  acc[6][2]=MFMA16x16x32(a2,b2,acc[6][2]); acc[7][2]=MFMA16x16x32(a3,b2,acc[7][2]); \
  acc[4][3]=MFMA16x16x32(a0,b3,acc[4][3]); acc[5][3]=MFMA16x16x32(a1,b3,acc[5][3]); \
  acc[6][3]=MFMA16x16x32(a2,b3,acc[6][3]); acc[7][3]=MFMA16x16x32(a3,b3,acc[7][3]);

template <int MODE>
__global__ __launch_bounds__(512, 2) void gemm256(const ushort_t* __restrict__ A,
                                                  const ushort_t* __restrict__ W,
                                                  const float* __restrict__ bias,
                                                  void* __restrict__ Cv,
                                                  int M, int Nout, int K, int KS,
                                                  int GN, int GM) {
    __shared__ ushort_t Ab[32768];   // [dbuf][kk-half][8192 elems]
    __shared__ ushort_t Bb[32768];
    int tid = threadIdx.x;
    int w  = tid >> 6, l = tid & 63;
    int li = l & 15,  g = l >> 4;
    int wm = w >> 2,  wn = w & 3;

    // ---- XCD-chunked decode ----
    int xcd = blockIdx.x & 7;
    int c   = blockIdx.x >> 3;
    int RN = GN >> 2, RM = GM >> 1;
    int rsz = RN * RM;
    int bz = c / rsz;
    int r  = c - bz * rsz;
    int bm = (xcd >> 2) * RM + r / RN;
    int bn = (xcd & 3) * RN + r % RN;

    // ---- staging source (pre-swizzled) ----
    int lc   = (l & 7) ^ (l >> 3);
    int sgr  = w * 32 + 2 * (l >> 3) + (lc >> 2);
    int colo = (lc & 3) * 8;
    const ushort_t* sA0 = A + (size_t)(bm * 256 + sgr) * K + bz * KS + colo;
    const ushort_t* sA1 = sA0 + (size_t)16 * K;
    const ushort_t* sB0 = W + (size_t)(bn * 256 + sgr) * K + bz * KS + colo;
    const ushort_t* sB1 = sB0 + (size_t)16 * K;

    // ---- read-side bases (bytes) ----
    uint_t chunkpos = (uint_t)(((((li & 1) << 2) + g) ^ (li >> 1)) << 4);
    uint_t aBase = (uint_t)(uintptr_t)(&Ab[0]) + (uint_t)(wm * 8192 + (li >> 1) * 128) + chunkpos;
    uint_t bBase = (uint_t)(uintptr_t)(&Bb[0]) + (uint_t)(wn * 4096 + (li >> 1) * 128) + chunkpos;

    f32x4 acc[8][4];
    #pragma unroll
    for (int i = 0; i < 8; i++)
        #pragma unroll
        for (int j = 0; j < 4; j++) acc[i][j] = (f32x4){0.f, 0.f, 0.f, 0.f};

    const int NT = KS >> 6;

    // ---- prologue: tile 0 -> dbuf 0, order Ah0,Bh0,Ah1,Bh1; vmcnt(4) ----
    {
        ushort_t* dA = &Ab[0] + w * 1024;
        ushort_t* dB = &Bb[0] + w * 1024;
        gload_lds16(sA0,      dA);        gload_lds16(sA1,      dA + 512);
        gload_lds16(sB0,      dB);        gload_lds16(sB1,      dB + 512);
        gload_lds16(sA0 + 32, dA + 8192); gload_lds16(sA1 + 32, dA + 8192 + 512);
        gload_lds16(sB0 + 32, dB + 8192); gload_lds16(sB1 + 32, dB + 8192 + 512);
    }
    asm volatile("s_waitcnt vmcnt(4)" ::);
    SB0; BARR;

    for (int t = 0; t < NT; ++t) {
        int d = t & 1;
        bool pf = (t + 1 < NT);
        int kn = (t + 1) * 64;
        uint_t aAddr = aBase + (uint_t)(d * 32768);
        uint_t bAddr = bBase + (uint_t)(d * 32768);
        ushort_t* dA = &Ab[0] + (d ^ 1) * 16384 + w * 1024;
        ushort_t* dB = &Bb[0] + (d ^ 1) * 16384 + w * 1024;
        bf16x8 a0, a1, a2, a3, b0, b1, b2, b3;

        // ---- phase 0: qm0, kk0 (8 reads; stage A-h0 of t+1) ----
        DSR(a0, aAddr, "0");    DSR(a1, aAddr, "1024");
        DSR(a2, aAddr, "2048"); DSR(a3, aAddr, "3072");
        DSR(b0, bAddr, "0");    DSR(b1, bAddr, "1024");
        DSR(b2, bAddr, "2048"); DSR(b3, bAddr, "3072");
        if (pf) { gload_lds16(sA0 + kn, dA); gload_lds16(sA1 + kn, dA + 512); }
        SB0; BARR; LGKM0; SB0;
        __builtin_amdgcn_s_setprio(1);
        MMQ0
        __builtin_amdgcn_s_setprio(0);
        SB0; BARR;

        // ---- phase 1: qm1, kk0 (4 reads; stage B-h0; vmcnt for t's kk1) ----
        DSR(a0, aAddr, "4096"); DSR(a1, aAddr, "5120");
        DSR(a2, aAddr, "6144"); DSR(a3, aAddr, "7168");
        if (pf) { gload_lds16(sB0 + kn, dB); gload_lds16(sB1 + kn, dB + 512); }
        SB0; BARR; LGKM0; SB0;
        __builtin_amdgcn_s_setprio(1);
        MMQ4
        __builtin_amdgcn_s_setprio(0);
        if (pf) { asm volatile("s_waitcnt vmcnt(4)" ::); }
        else    { asm volatile("s_waitcnt vmcnt(0)" ::); }
        SB0; BARR;

        // ---- phase 2: qm0, kk1 (8 reads; stage A-h1) ----
        DSR(a0, aAddr, "16384"); DSR(a1, aAddr, "17408");
        DSR(a2, aAddr, "18432"); DSR(a3, aAddr, "19456");
        DSR(b0, bAddr, "16384"); DSR(b1, bAddr, "17408");
        DSR(b2, bAddr, "18432"); DSR(b3, bAddr, "19456");
        if (pf) { gload_lds16(sA0 + kn + 32, dA + 8192); gload_lds16(sA1 + kn + 32, dA + 8192 + 512); }
        SB0; BARR; LGKM0; SB0;
        __builtin_amdgcn_s_setprio(1);
        MMQ0
        __builtin_amdgcn_s_setprio(0);
        SB0; BARR;

        // ---- phase 3: qm1, kk1 (4 reads; stage B-h1; vmcnt for t+1's kk0) ----
        DSR(a0, aAddr, "20480"); DSR(a1, aAddr, "21504");
        DSR(a2, aAddr, "22528"); DSR(a3, aAddr, "23552");
        if (pf) { gload_lds16(sB0 + kn + 32, dB + 8192); gload_lds16(sB1 + kn + 32, dB + 8192 + 512); }
        SB0; BARR; LGKM0; SB0;
        __builtin_amdgcn_s_setprio(1);
        MMQ4
        __builtin_amdgcn_s_setprio(0);
        asm volatile("s_waitcnt vmcnt(4)" ::);
        SB0; BARR;
    }

    // ---- epilogue ----
    #pragma unroll
    for (int fm = 0; fm < 8; fm++) {
        #pragma unroll
        for (int fn = 0; fn < 4; fn++) {
            int nn = bn * 256 + wn * 64 + fn * 16 + li;
            int mB = bm * 256 + wm * 128 + (fm >> 2) * 64 + (fm & 3) * 16 + g * 4;
            if (MODE == 0) {
                int which = nn >> 10, col = nn & 1023;
                int h = col >> 6, dd = col & 63;
                int b = mB >> 11, n0 = mB & (Nmod - 1);
                ushort_t* C = (ushort_t*)Cv;
                if (which == 2) {
                    // V^T: 4 consecutive n -> vectorized 8B store
                    uint2 pk;
                    pk.x = (uint_t)f2bf(acc[fm][fn][0]) | ((uint_t)f2bf(acc[fm][fn][1]) << 16);
                    pk.y = (uint_t)f2bf(acc[fm][fn][2]) | ((uint_t)f2bf(acc[fm][fn][3]) << 16);
                    *(uint2*)(C + 8388608u + (((size_t)(b * NHmod + h)) * DHmod + dd) * Nmod + n0) = pk;
                } else {
                    #pragma unroll
                    for (int r2 = 0; r2 < 4; r2++) {
                        size_t idx = (size_t)which * 4194304u +
                                     (((size_t)(b * NHmod + h)) * Nmod + n0 + r2) * DHmod + dd;
                        C[idx] = f2bf(acc[fm][fn][r2]);
                    }
                }
            } else if (MODE == 2) {
                ushort_t* C = (ushort_t*)Cv;
                #pragma unroll
                for (int r2 = 0; r2 < 4; r2++)
                    C[(size_t)(mB + r2) * Nout + nn] = f2bf(gelu_f(acc[fm][fn][r2] + bias[nn]));
            } else {  // MODE 4
                ushort_t* P = (ushort_t*)Cv + (size_t)bz * M * Nout;
                #pragma unroll
                for (int r2 = 0; r2 < 4; r2++)
                    P[(size_t)(mB + r2) * Nout + nn] = f2bf(acc[fm][fn][r2]);
            }
        }
    }
}

// ---------------- bf16 MFMA GEMM (round-12, kept for Wo split-K) ----------------
template <int MODE, int BN>
__global__ __launch_bounds__(256) void bgemm(const ushort_t* __restrict__ A,
                                             const ushort_t* __restrict__ W,
                                             const float* __restrict__ bias,
                                             const float* __restrict__ resid,
                                             void* __restrict__ Cv,
                                             int M, int Nout, int K, int KS,
                                             int GN, int GM) {
    const int BSZ = BN * 32;
    const int NFR = BN / 32;
    __shared__ ushort_t As[3 * 4096];
    __shared__ ushort_t Bs[3 * BSZ];
    int tid  = threadIdx.x;
    int w    = tid >> 6, lane = tid & 63;
    int li   = lane & 15, g = lane >> 4;
    int wr   = w >> 1,  wc = w & 1;

    int xcd = blockIdx.x & 7;
    int c   = blockIdx.x >> 3;
    int RN  = GN >> 2;
    int RM  = GM >> 1;
    int rsz = RN * RM;
    int bz  = c / rsz;
    int r   = c - bz * rsz;
    int bm  = (xcd >> 2) * RM + r / RN;
    int bn  = (xcd & 3) * RN + r % RN;

    int srow = tid >> 2;
    int scol = ((tid & 3) ^ ((tid >> 3) & 3)) * 8;
    const ushort_t* Ag = A + (size_t)(bm * 128 + srow) * K + bz * KS + scol;
    const ushort_t* Wg = W + (size_t)(bn * BN  + srow) * K + bz * KS + scol;
    ushort_t* AsW = As + w * 512;
    ushort_t* BsW = Bs + w * 512;

    int rsw = ((g ^ ((li >> 1) & 3)) * 8);

    uint_t lbA = (uint_t)(uintptr_t)(&As[0]);
    uint_t lbB = (uint_t)(uintptr_t)(&Bs[0]);
    uint_t abase = lbA + (uint_t)(((wr * 64 + li) * 32 + rsw) * 2);
    uint_t bbase = lbB + (uint_t)(((wc * (BN / 2) + li) * 32 + rsw) * 2);

    f32x4 acc[4][NFR];
    #pragma unroll
    for (int i = 0; i < 4; i++)
        #pragma unroll
        for (int j = 0; j < NFR; j++) acc[i][j] = (f32x4){0.f, 0.f, 0.f, 0.f};

    const int NT = KS >> 5;

    auto stagef = [&](int bufA, int bufB, int t) {
        int k0 = t * 32;
        gload_lds16(Ag + k0,          AsW + bufA);
        gload_lds16(Ag + 64 * K + k0, AsW + bufA + 2048);
        gload_lds16(Wg + k0,          BsW + bufB);
        if (BN == 128) gload_lds16(Wg + 64 * K + k0, BsW + bufB + 2048);
    };

    stagef(0, 0, 0);
    stagef(4096, BSZ, 1);

    int curA = 0, curB = 0;
    int stgA = 8192, stgB = 2 * BSZ;

    for (int t = 0; t < NT; ++t) {
        if (t == NT - 1) { asm volatile("s_waitcnt vmcnt(0)" ::); }
        else if (BN == 128) { asm volatile("s_waitcnt vmcnt(4)" ::); }
        else { asm volatile("s_waitcnt vmcnt(3)" ::); }
        __builtin_amdgcn_s_barrier();
        __builtin_amdgcn_sched_barrier(0);
        if (t + 2 < NT) stagef(stgA, stgB, t + 2);
        __builtin_amdgcn_sched_barrier(0);
        bf16x8 af[4], bfr[NFR];
        uint_t aa = abase + (uint_t)(curA * 2);
        uint_t bb = bbase + (uint_t)(curB * 2);
        asm volatile("ds_read_b128 %0, %1"             : "=v"(af[0]) : "v"(aa));
        asm volatile("ds_read_b128 %0, %1 offset:1024" : "=v"(af[1]) : "v"(aa));
        asm volatile("ds_read_b128 %0, %1 offset:2048" : "=v"(af[2]) : "v"(aa));
        asm volatile("ds_read_b128 %0, %1 offset:3072" : "=v"(af[3]) : "v"(aa));
        asm volatile("ds_read_b128 %0, %1"             : "=v"(bfr[0]) : "v"(bb));
        asm volatile("ds_read_b128 %0, %1 offset:1024" : "=v"(bfr[1]) : "v"(bb));
        if (NFR == 4) {
            asm volatile("ds_read_b128 %0, %1 offset:2048" : "=v"(bfr[2]) : "v"(bb));
            asm volatile("ds_read_b128 %0, %1 offset:3072" : "=v"(bfr[3]) : "v"(bb));
        }
        asm volatile("s_waitcnt lgkmcnt(0)" ::);
        __builtin_amdgcn_sched_barrier(0);
        __builtin_amdgcn_s_setprio(1);
        #pragma unroll
        for (int mi = 0; mi < 4; mi++)
            #pragma unroll
            for (int ni = 0; ni < NFR; ni++)
                acc[mi][ni] = MFMA16x16x32(af[mi], bfr[ni], acc[mi][ni]);
        __builtin_amdgcn_s_setprio(0);
        curA = (curA == 8192) ? 0 : curA + 4096;
        curB = (curB == 2 * BSZ) ? 0 : curB + BSZ;
        stgA = (stgA == 8192) ? 0 : stgA + 4096;
        stgB = (stgB == 2 * BSZ) ? 0 : stgB + BSZ;
    }

    #pragma unroll
    for (int mi = 0; mi < 4; mi++) {
        #pragma unroll
        for (int ni = 0; ni < NFR; ni++) {
            int nn = bn * BN + wc * (BN / 2) + ni * 16 + li;
            #pragma unroll
            for (int r2 = 0; r2 < 4; r2++) {
                int m = bm * 128 + wr * 64 + mi * 16 + g * 4 + r2;
                float v = acc[mi][ni][r2];
                if (MODE == 1) {
                    float* C = (float*)Cv;
                    C[(size_t)m * Nout + nn] = v + bias[nn] + resid[(size_t)m * Nout + nn];
                } else if (MODE == 3) {
                    float* C = (float*)Cv + (size_t)bz * M * Nout;
                    C[(size_t)m * Nout + nn] = v;
                }
            }
        }
    }
}

// ---------------- split-K reduce + residual + LN (Wo path) ----------------
__global__ __launch_bounds__(256) void red_ln_kernel(const float* __restrict__ p,
                                                     const float* __restrict__ x,
                                                     const float* __restrict__ bo,
                                                     const float* __restrict__ scale,
                                                     const float* __restrict__ shift,
                                                     float* __restrict__ x1,
                                                     ushort_t* __restrict__ h2) {
    int row = blockIdx.x;
    int t   = threadIdx.x;
    const size_t MD = (size_t)Mrows * Dmod;
    float4 a = ((const float4*)(p + (size_t)row * Dmod))[t];
    float4 b = ((const float4*)(p + MD + (size_t)row * Dmod))[t];
    float4 xr = ((const float4*)(x + (size_t)row * Dmod))[t];
    float4 bb = ((const float4*)bo)[t];
    float4 v;
    v.x = a.x + b.x + xr.x + bb.x;
    v.y = a.y + b.y + xr.y + bb.y;
    v.z = a.z + b.z + xr.z + bb.z;
    v.w = a.w + b.w + xr.w + bb.w;
    ((float4*)(x1 + (size_t)row * Dmod))[t] = v;

    float s  = v.x + v.y + v.z + v.w;
    float s2 = v.x*v.x + v.y*v.y + v.z*v.z + v.w*v.w;
    __shared__ float rs[8], rs2[8];
    #pragma unroll
    for (int o = 32; o; o >>= 1) { s += __shfl_down(s, o); s2 += __shfl_down(s2, o); }
    int wave = t >> 6, lane = t & 63;
    if (lane == 0) { rs[wave] = s; rs2[wave] = s2; }
    __syncthreads();
    if (t == 0) {
        rs[0]  = rs[0] + rs[1] + rs[2] + rs[3];
        rs2[0] = rs2[0] + rs2[1] + rs2[2] + rs2[3];
    }
    __syncthreads();
    float mean = rs[0] * (1.0f / Dmod);
    float var  = rs2[0] * (1.0f / Dmod) - mean * mean;
    float rstd = rsqrtf(var + EPSLN);

    float4 sc = ((const float4*)scale)[t];
    float4 sh = ((const float4*)shift)[t];
    uint2 o;
    o.x = (uint_t)f2bf(sc.x * (v.x - mean) * rstd + sh.x) |
          ((uint_t)f2bf(sc.y * (v.y - mean) * rstd + sh.y) << 16);
    o.y = (uint_t)f2bf(sc.z * (v.z - mean) * rstd + sh.z) |
          ((uint_t)f2bf(sc.w * (v.w - mean) * rstd + sh.w) << 16);
    ((uint2*)(h2 + (size_t)row * Dmod))[t] = o;
}

// ---------------- 4-way bf16 split-K reduce + bias + residual (FFN-down) ----------------
__global__ __launch_bounds__(256) void red_out4_kernel(const ushort_t* __restrict__ p,
                                                       const float* __restrict__ x1,
                                                       const float* __restrict__ b2,
                                                       float* __restrict__ out) {
    const size_t MD4 = (size_t)Mrows * Dmod / 4;
    size_t i = (size_t)blockIdx.x * 256 + threadIdx.x;
    if (i >= MD4) return;
    float4 xr = ((const float4*)x1)[i];
    float4 bb = ((const float4*)b2)[i & 255];
    float4 v;
    v.x = xr.x + bb.x; v.y = xr.y + bb.y; v.z = xr.z + bb.z; v.w = xr.w + bb.w;
    #pragma unroll
    for (int z = 0; z < 4; z++) {
        uint2 pk = ((const uint2*)(p + (size_t)z * Mrows * Dmod))[i];
        v.x += bf2f(pk.x & 0xffffu);
        v.y += bf2f(pk.x >> 16);
        v.z += bf2f(pk.y & 0xffffu);
        v.w += bf2f(pk.y >> 16);
    }
    ((float4*)out)[i] = v;
}

// ---------------- Flash attention v4 (unchanged) ----------------
__global__ __launch_bounds__(256) void fattn_kernel(const ushort_t* __restrict__ Q,
                                                    const ushort_t* __restrict__ K,
                                                    const ushort_t* __restrict__ VT,
                                                    ushort_t* __restrict__ O) {
    int bid = blockIdx.x;
    int xcd = bid & 7;
    int j   = bid >> 3;
    int bh  = xcd * 4 + (j & 3);
    int qt  = 31 - (j >> 2);
    int b   = bh >> 4, hh = bh & 15;
    int w    = threadIdx.x >> 6;
    int lane = threadIdx.x & 63;
    int li   = lane & 15;
    int g    = lane >> 4;

    __shared__ ushort_t Klds[2][4096];
    __shared__ ushort_t Vlds[2][4096];
    __shared__ ushort_t Plds[4][16][72];

    int q0 = qt * 64 + w * 16;
    int q  = q0 + li;

    const ushort_t* Qb = Q  + (size_t)bh * Nmod * DHmod;
    const ushort_t* Kb = K  + (size_t)bh * Nmod * DHmod;
    const ushort_t* Vb = VT + (size_t)bh * DHmod * Nmod;

    bf16x8 qf[2];
    #pragma unroll
    for (int c = 0; c < 2; c++)
        qf[c] = *(const bf16x8*)(Qb + (size_t)q * DHmod + c * 32 + g * 8);

    f32x4 po[4];
    #pragma unroll
    for (int mt = 0; mt < 4; mt++) po[mt] = (f32x4){0.f, 0.f, 0.f, 0.f};
    float l = 0.f;

    const int ntiles = qt + 1;

    int r_sub = lane >> 3;
    int cc    = ((lane & 7) ^ (r_sub & 7)) * 8;

    int swz  = (li & 7) * 8;
    int roff = li * 64;
    int c0k  = (g * 8) ^ swz;
    int c1k  = (32 + g * 8) ^ swz;

    auto stage = [&](int buf, int kt) {
        int k0 = kt * 64;
        #pragma unroll
        for (int i2 = 0; i2 < 2; i2++) {
            int i   = w * 2 + i2;
            int row = i * 8 + r_sub;
            gload_lds16(Kb + (size_t)(k0 + row) * DHmod + cc, &Klds[buf][i * 512]);
            gload_lds16(Vb + (size_t)row * Nmod + k0 + cc,    &Vlds[buf][i * 512]);
        }
    };

    stage(0, 0);

    for (int kt = 0; kt < ntiles; ++kt) {
        __syncthreads();
        if (kt + 1 < ntiles) stage((kt + 1) & 1, kt + 1);
        int cur = kt & 1;
        int k0  = kt * 64;

        f32x4 s[4];
        __builtin_amdgcn_s_setprio(1);
        #pragma unroll
        for (int mt = 0; mt < 4; mt++) {
            bf16x8 kf0 = *(const bf16x8*)&Klds[cur][mt * 1024 + roff + c0k];
            bf16x8 kf1 = *(const bf16x8*)&Klds[cur][mt * 1024 + roff + c1k];
            s[mt] = (f32x4){0.f, 0.f, 0.f, 0.f};
            s[mt] = MFMA16x16x32(kf0, qf[0], s[mt]);
            s[mt] = MFMA16x16x32(kf1, qf[1], s[mt]);
        }
        __builtin_amdgcn_s_setprio(0);

        if (kt == qt) {
            #pragma unroll
            for (int mt = 0; mt < 4; mt++)
                #pragma unroll
                for (int r = 0; r < 4; r++)
                    if (k0 + mt * 16 + g * 4 + r > q) s[mt][r] = -INFINITY;
        }
        float ptile = 0.f;
        #pragma unroll
        for (int mt = 0; mt < 4; mt++) {
            float p0 = __expf(s[mt][0]);
            float p1 = __expf(s[mt][1]);
            float p2 = __expf(s[mt][2]);
            float p3 = __expf(s[mt][3]);
            ptile += (p0 + p1) + (p2 + p3);
            uint2 pk;
            pk.x = (uint_t)f2bf(p0) | ((uint_t)f2bf(p1) << 16);
            pk.y = (uint_t)f2bf(p2) | ((uint_t)f2bf(p3) << 16);
            *(uint2*)&Plds[w][li][mt * 16 + g * 4] = pk;
        }
        l += ptile;

        asm volatile("" ::: "memory");

        bf16x8 pf0 = *(const bf16x8*)&Plds[w][li][g * 8];
        bf16x8 pf1 = *(const bf16x8*)&Plds[w][li][32 + g * 8];
        __builtin_amdgcn_s_setprio(1);
        #pragma unroll
        for (int mt = 0; mt < 4; mt++) {
            bf16x8 vf0 = *(const bf16x8*)&Vlds[cur][mt * 1024 + roff + c0k];
            bf16x8 vf1 = *(const bf16x8*)&Vlds[cur][mt * 1024 + roff + c1k];
            po[mt] = MFMA16x16x32(vf0, pf0, po[mt]);
            po[mt] = MFMA16x16x32(vf1, pf1, po[mt]);
        }
        __builtin_amdgcn_s_setprio(0);
        asm volatile("" ::: "memory");
    }

    l += __shfl_xor(l, 16);
    l += __shfl_xor(l, 32);
    float inv = 1.0f / l;
    ushort_t* Orow = O + ((size_t)(b * Nmod + q)) * Dmod + hh * DHmod;
    #pragma unroll
    for (int mt = 0; mt < 4; mt++) {
        uint2 pk;
        pk.x = (uint_t)f2bf(po[mt][0] * inv) | ((uint_t)f2bf(po[mt][1] * inv) << 16);
        pk.y = (uint_t)f2bf(po[mt][2] * inv) | ((uint_t)f2bf(po[mt][3] * inv) << 16);
        *(uint2*)(Orow + mt * 16 + g * 4) = pk;
    }
}

// ---------------- launcher ----------------
extern "C" void kernel_launch(void* const* d_in, const int* in_sizes, int n_in,
                              void* d_out, int out_size, void* d_ws, size_t ws_size,
                              hipStream_t stream) {
    const float* x    = (const float*)d_in[0];
    const float* Wq   = (const float*)d_in[1];
    const float* Wk   = (const float*)d_in[2];
    const float* Wv   = (const float*)d_in[3];
    const float* Wo   = (const float*)d_in[4];
    const float* bo   = (const float*)d_in[5];
    const float* ln1s = (const float*)d_in[6];
    const float* ln1b = (const float*)d_in[7];
    const float* ln2s = (const float*)d_in[8];
    const float* ln2b = (const float*)d_in[9];
    const float* W1   = (const float*)d_in[10];
    const float* b1   = (const float*)d_in[11];
    const float* W2   = (const float*)d_in[12];
    const float* b2   = (const float*)d_in[13];
    float* out = (float*)d_out;
    char*  wsb = (char*)d_ws;

    // workspace layout (112 MB)
    ushort_t* h_bf  = (ushort_t*)wsb;                  // 8MB  LN1 out; reused as att
    ushort_t* qb    = (ushort_t*)(wsb + (8u  << 20));  // 8MB  Q
    ushort_t* kb    = qb + 4194304;                    // 8MB  K
    ushort_t* vtb   = qb + 8388608;                    // 8MB  V^T
    float*    x1    = (float*)(wsb + (32u << 20));     // 16MB x + attn
    ushort_t* h2_bf = (ushort_t*)(wsb + (48u << 20));  // 8MB  LN2 out
    ushort_t* g_bf  = (ushort_t*)(wsb + (56u << 20));  // 32MB FFN hidden
    ushort_t* wqkv  = (ushort_t*)(wsb + (88u << 20));  // 6MB
    ushort_t* wo_b  = (ushort_t*)(wsb + (94u << 20));  // 2MB
    ushort_t* w1_b  = (ushort_t*)(wsb + (96u << 20));  // 8MB
    ushort_t* w2_b  = (ushort_t*)(wsb + (104u << 20)); // 8MB
    ushort_t* att   = h_bf;
    // split-K partial regions:
    float*    pWo = (float*)(wsb + (56u << 20));       // 2 x 16MB fp32 (g region)
    ushort_t* pFd = (ushort_t*)wsb;                    // 4 x 8MB bf16 (h/q/k/v region)

    cvt_kernel<<<6144, 256, 0, stream>>>(Wq, Wk, Wv, Wo, W1, W2, wqkv, wo_b, w1_b, w2_b);
    ln_bf_kernel<<<Mrows, 256, 0, stream>>>(x, ln1s, ln1b, h_bf);
    // QKV: 8-phase 256x256, GN=12, GM=16 -> 192 blocks
    gemm256<0><<<192, 512, 0, stream>>>(h_bf, wqkv, nullptr, qb, Mrows, 3072, Dmod, Dmod, 12, 16);
    fattn_kernel<<<1024, 256, 0, stream>>>(qb, kb, vtb, att);
    // Wo split-K=2 (128-tile kernel): GN=16, GM=32, z=2 -> 1024 blocks
    bgemm<3, 64><<<1024, 256, 0, stream>>>(att, wo_b, nullptr, nullptr, pWo, Mrows, Dmod, Dmod, Dmod / 2, 16, 32);
    red_ln_kernel<<<Mrows, 256, 0, stream>>>(pWo, x, bo, ln2s, ln2b, x1, h2_bf);
    // FFN up: 8-phase 256x256, GN=16, GM=16 -> 256 blocks
    gemm256<2><<<256, 512, 0, stream>>>(h2_bf, w1_b, b1, g_bf, Mrows, FF, Dmod, Dmod, 16, 16);
    // FFN down: 8-phase 256x256, split-K=4 (bf16 partials), GN=4, GM=16 -> 256 blocks
    gemm256<4><<<256, 512, 0, stream>>>(g_bf, w2_b, nullptr, pFd, Mrows, Dmod, FF, FF / 4, 4, 16);
    red_out4_kernel<<<(Mrows * Dmod / 4 + 255) / 256, 256, 0, stream>>>(pFd, x1, b2, out);
}